// Round 7
// baseline (244.251 us; speedup 1.0000x reference)
//
#include <hip/hip_runtime.h>
#include <hip/hip_bf16.h>

#define DIM 512
#define SEQ 2048
#define BATCH 4
#define NHEADS 8
#define DH 64
#define NROWS (BATCH * SEQ)
#define LN_EPS 1e-5f

typedef __hip_bfloat16 bf16;
typedef __attribute__((ext_vector_type(8))) short short8;
typedef __attribute__((ext_vector_type(4))) float f32x4;

#define MFMA16(a, b, c) __builtin_amdgcn_mfma_f32_16x16x32_bf16((a), (b), (c), 0, 0, 0)

#if __has_builtin(__builtin_amdgcn_exp2f)
#define EXP2(x) __builtin_amdgcn_exp2f(x)
#else
#define EXP2(x) exp2f(x)
#endif

#if defined(__has_builtin)
#if __has_builtin(__builtin_amdgcn_global_load_lds)
#define HAS_GLDS 1
#endif
#endif

// async global->LDS, 16B per lane; LDS dest = wave-uniform base + lane*16
__device__ __forceinline__ void glds16(const bf16* g, bf16* l) {
#ifdef HAS_GLDS
  __builtin_amdgcn_global_load_lds((const __attribute__((address_space(1))) void*)g,
                                   (__attribute__((address_space(3))) void*)l, 16, 0, 0);
#else
  *reinterpret_cast<uint4*>(l) = *reinterpret_cast<const uint4*>(g);
#endif
}

__device__ __forceinline__ void store_bf16x4(bf16* p, float a, float b, float c, float d) {
  bf16 tmp[4] = {__float2bfloat16(a), __float2bfloat16(b), __float2bfloat16(c),
                 __float2bfloat16(d)};
  *reinterpret_cast<ushort4*>(p) = *reinterpret_cast<const ushort4*>(tmp);
}

// scale * log2(e), folded into Wq so attention's softmax is a bare v_exp_f32
#define Q_SCALE_LOG2E 0.06375872f

// ---------------- LayerNorm + cast to bf16 ----------------
__global__ void ln_kernel(const float* __restrict__ x, const float* __restrict__ gamma,
                          const float* __restrict__ beta, bf16* __restrict__ xn) {
  const int row = blockIdx.x;
  const int t = threadIdx.x;  // 256 threads, 2 elems each
  const float2 v = reinterpret_cast<const float2*>(x + (size_t)row * DIM)[t];
  float s = v.x + v.y;
  float ss = v.x * v.x + v.y * v.y;
#pragma unroll
  for (int off = 32; off > 0; off >>= 1) {
    s += __shfl_down(s, off);
    ss += __shfl_down(ss, off);
  }
  __shared__ float red[8];
  __shared__ float stats[2];
  if ((t & 63) == 0) { red[(t >> 6) * 2] = s; red[(t >> 6) * 2 + 1] = ss; }
  __syncthreads();
  if (t == 0) {
    float S = red[0] + red[2] + red[4] + red[6];
    float SS = red[1] + red[3] + red[5] + red[7];
    float mu = S * (1.0f / DIM);
    float var = SS * (1.0f / DIM) - mu * mu;
    stats[0] = mu;
    stats[1] = rsqrtf(var + LN_EPS);
  }
  __syncthreads();
  const float mu = stats[0], rs = stats[1];
  const float2 gg = reinterpret_cast<const float2*>(gamma)[t];
  const float2 bb = reinterpret_cast<const float2*>(beta)[t];
  __hip_bfloat162 o;
  o.x = __float2bfloat16((v.x - mu) * rs * gg.x + bb.x);
  o.y = __float2bfloat16((v.y - mu) * rs * gg.y + bb.y);
  reinterpret_cast<__hip_bfloat162*>(xn + (size_t)row * DIM)[t] = o;
}

// -------- All 4 weight transposes in one launch: W[K][N] fp32 -> Wt[N][K] bf16 * scale --------
__global__ void wt_all_kernel(const float* __restrict__ Wq, const float* __restrict__ Wk,
                              const float* __restrict__ Wv, const float* __restrict__ Wo,
                              bf16* __restrict__ Wt) {
  const int z = blockIdx.z;
  const float* __restrict__ W = (z == 0) ? Wq : (z == 1) ? Wk : (z == 2) ? Wv : Wo;
  const float scale = (z == 0) ? Q_SCALE_LOG2E : 1.0f;
  bf16* __restrict__ dst = Wt + (size_t)z * DIM * DIM;
  __shared__ float tile[32][33];
  const int bx = blockIdx.x, by = blockIdx.y;  // bx: n-tile, by: k-tile
  const int tx = threadIdx.x & 31, ty = threadIdx.x >> 5;  // 32 x 8
#pragma unroll
  for (int i = 0; i < 32; i += 8)
    tile[ty + i][tx] = W[(size_t)(by * 32 + ty + i) * DIM + bx * 32 + tx];
  __syncthreads();
#pragma unroll
  for (int i = 0; i < 32; i += 8)
    dst[(size_t)(bx * 32 + ty + i) * DIM + by * 32 + tx] =
        __float2bfloat16(tile[tx][ty + i] * scale);
}

// ------ Fused QKV GEMM: C[M,1536] = A[M,512] @ Wt[1536,512]^T, 128x128 tile, dbuf ------
// q,k written [b][n][512]; V written TRANSPOSED [b][512][seq] via LDS-staged epilogue.
__launch_bounds__(256, 3)
__global__ void gemm_qkv_kernel(const bf16* __restrict__ A, const bf16* __restrict__ Bt,
                                bf16* __restrict__ qo, bf16* __restrict__ ko,
                                bf16* __restrict__ vto) {
  const int m0 = blockIdx.x * 128, n0g = blockIdx.y * 128;
  // union: K-loop uses sA/sB dbuf (32 KB); z==2 epilogue reuses as 128x136 transpose tile
  __shared__ __align__(16) char smem[128 * 136 * 2];  // 34816 B
  bf16* const sA = (bf16*)smem;               // [2][128*32]
  bf16* const sB = (bf16*)(smem + 16384);     // [2][128*32]
  bf16* const sT = (bf16*)smem;               // [128][136]
  const int t = threadIdx.x, w = t >> 6, l = t & 63;
  const int r = l & 15, g = l >> 4;
  const int wm = w >> 1, wn = w & 1;
  const int crow = w * 32 + (l >> 2);
  const int ccol = (l & 3) * 8;
  const bf16* gA = A + (size_t)(m0 + crow) * DIM + ccol;
  const bf16* gB = Bt + (size_t)(n0g + crow) * DIM + ccol;
  const int loff = w * 1024 + l * 8;
  f32x4 acc[4][4] = {};
  glds16(gA, sA + loff);
  glds16(gA + 16 * DIM, sA + loff + 512);
  glds16(gB, sB + loff);
  glds16(gB + 16 * DIM, sB + loff + 512);
  const int NK = DIM / 32;
  for (int ks = 0; ks < NK; ks++) {
    const int cur = ks & 1;
    __syncthreads();  // buf[cur] ready (drains vmcnt); all reads of buf[1-cur] done
    if (ks + 1 < NK) {
      const int k0n = (ks + 1) * 32;
      glds16(gA + k0n, sA + (1 - cur) * 4096 + loff);
      glds16(gA + 16 * DIM + k0n, sA + (1 - cur) * 4096 + loff + 512);
      glds16(gB + k0n, sB + (1 - cur) * 4096 + loff);
      glds16(gB + 16 * DIM + k0n, sB + (1 - cur) * 4096 + loff + 512);
    }
    short8 af[4], bfv[4];
#pragma unroll
    for (int i = 0; i < 4; i++)
      af[i] = *reinterpret_cast<const short8*>(
          &sA[cur * 4096 + (wm * 64 + i * 16 + r) * 32 + g * 8]);
#pragma unroll
    for (int j = 0; j < 4; j++)
      bfv[j] = *reinterpret_cast<const short8*>(
          &sB[cur * 4096 + (wn * 64 + j * 16 + r) * 32 + g * 8]);
#pragma unroll
    for (int i = 0; i < 4; i++)
#pragma unroll
      for (int j = 0; j < 4; j++) acc[i][j] = MFMA16(af[i], bfv[j], acc[i][j]);
  }
  const int z = n0g >> 9;  // which of q/k/v this n-tile belongs to
  const int b = m0 / SEQ;  // 128 | SEQ so whole block shares b
  if (z != 2) {
    bf16* __restrict__ outp = (z == 0) ? qo : ko;
    const int nc0 = (n0g & 511) + wn * 64;
#pragma unroll
    for (int i = 0; i < 4; i++)
#pragma unroll
      for (int j = 0; j < 4; j++)
#pragma unroll
        for (int reg = 0; reg < 4; reg++) {
          const int m = m0 + wm * 64 + i * 16 + g * 4 + reg;
          const int col = nc0 + j * 16 + r;
          outp[(size_t)m * DIM + col] = __float2bfloat16(acc[i][j][reg]);
        }
  } else {
    // transpose epilogue: acc -> sT[n][m] -> coalesced V^T writes (16B along seq)
    __syncthreads();  // done with sA/sB
#pragma unroll
    for (int i = 0; i < 4; i++)
#pragma unroll
      for (int j = 0; j < 4; j++)
        store_bf16x4(&sT[(wn * 64 + j * 16 + r) * 136 + wm * 64 + i * 16 + g * 4],
                     acc[i][j][0], acc[i][j][1], acc[i][j][2], acc[i][j][3]);
    __syncthreads();
    const int dr = t >> 1;             // 0..127: d-row within this 128-wide n-tile
    const int mc = (t & 1) * 64;       // m-half
    const int dcol = (n0g & 511) + dr;
    bf16* dst = vto + ((size_t)b * DIM + dcol) * SEQ + (m0 - b * SEQ) + mc;
#pragma unroll
    for (int uu = 0; uu < 8; uu++)
      *reinterpret_cast<uint4*>(dst + uu * 8) =
          *reinterpret_cast<const uint4*>(&sT[dr * 136 + mc + uu * 8]);
  }
}

// -------- Flash attention: S^T/O^T form, LDS-free K/V (direct global frags), no barriers --------
// block = 128 thr (2 waves), 64 q-rows x one (b,h); wave owns 32 q-rows (2 strips of 16).
// S^T = MFMA(K-frag, Q-frag): P^T C-layout has i = lane&15 fixed -> scalar denominator,
// b64 sPt writes; PV: O^T = MFMA(V^T-frag, P^T-frag). K/V frags are 16B contiguous global
// reads (L1/L2-hot), register-prefetched one j-tile ahead. Only LDS: wave-private sPt.
// Q pre-scaled by scale*log2e -> p = exp2(S). SPLIT: grid.z=2 j-halves write partials.
template <bool SPLIT>
__launch_bounds__(128, 3)
__global__ void attn_kernel(const bf16* __restrict__ q, const bf16* __restrict__ k,
                            const bf16* __restrict__ vt, bf16* __restrict__ ao,
                            bf16* __restrict__ opart, float* __restrict__ lpart) {
  const int it = blockIdx.x, bh = blockIdx.y, jh = blockIdx.z;
  const int b = bh >> 3, h = bh & 7;
  const int t = threadIdx.x, wv = t >> 6, l = t & 63;
  const int r = l & 15, g = l >> 4;
  __shared__ __align__(16) bf16 sPt[2][2][16][76];  // [wave][strip][i][j+pad]; wave-private
  const int i0 = it * 64 + wv * 32;
  // Q B-frags: lane holds Q[i = i0+s*16+r][d = kc*32 + g*8 ..+7]
  const bf16* qp = q + ((size_t)(b * SEQ) + i0 + r) * DIM + h * DH;
  short8 qf[2][2];
#pragma unroll
  for (int s = 0; s < 2; s++)
#pragma unroll
    for (int kc = 0; kc < 2; kc++)
      qf[s][kc] = *reinterpret_cast<const short8*>(qp + s * 16 * DIM + kc * 32 + g * 8);
  f32x4 oacc[2][4] = {};       // O^T C-layout: row d = dt*16+g*4+reg, col i = r
  float lsum[2] = {0.f, 0.f};  // denominator partial for row i (fixed per lane)
  const int jbase = SPLIT ? jh * (SEQ / 2) : 0;
  // per-lane global frag bases
  const bf16* kl = k + ((size_t)(b * SEQ) + jbase + r) * DIM + h * DH + g * 8;
  const bf16* vl = vt + ((size_t)(b * DIM) + h * DH + r) * SEQ + jbase + g * 8;
  uint4 kr[8], vr[8];  // K-frags [c][half], V-frags [dt][kc2] for current j-tile
#pragma unroll
  for (int c = 0; c < 4; c++)
#pragma unroll
    for (int hf = 0; hf < 2; hf++)
      kr[c * 2 + hf] = *reinterpret_cast<const uint4*>(kl + (size_t)(c * 16) * DIM + hf * 32);
#pragma unroll
  for (int dt = 0; dt < 4; dt++)
#pragma unroll
    for (int kc2 = 0; kc2 < 2; kc2++)
      vr[dt * 2 + kc2] =
          *reinterpret_cast<const uint4*>(vl + (size_t)(dt * 16) * SEQ + kc2 * 32);
  const int NJ = SPLIT ? (SEQ / 2) / 64 : SEQ / 64;
  for (int jt = 0; jt < NJ; jt++) {
    // S^T = K @ Q^T
    f32x4 st[2][4];
#pragma unroll
    for (int c = 0; c < 4; c++) {
      const short8 kf0 = *reinterpret_cast<const short8*>(&kr[c * 2 + 0]);
      const short8 kf1 = *reinterpret_cast<const short8*>(&kr[c * 2 + 1]);
#pragma unroll
      for (int s = 0; s < 2; s++) {
        f32x4 a = {0.f, 0.f, 0.f, 0.f};
        a = MFMA16(kf0, qf[s][0], a);
        a = MFMA16(kf1, qf[s][1], a);
        st[s][c] = a;
      }
    }
    // prefetch next K tile (latency covered by exp + PV below)
    if (jt + 1 < NJ) {
      const int jo = (jt + 1) * 64;
#pragma unroll
      for (int c = 0; c < 4; c++)
#pragma unroll
        for (int hf = 0; hf < 2; hf++)
          kr[c * 2 + hf] =
              *reinterpret_cast<const uint4*>(kl + (size_t)(jo + c * 16) * DIM + hf * 32);
    }
    // p = exp2(S^T); scalar denominator; b64 P^T writes (4 consecutive j)
#pragma unroll
    for (int s = 0; s < 2; s++)
#pragma unroll
      for (int c = 0; c < 4; c++) {
        const float p0 = EXP2(st[s][c][0]);
        const float p1 = EXP2(st[s][c][1]);
        const float p2 = EXP2(st[s][c][2]);
        const float p3 = EXP2(st[s][c][3]);
        lsum[s] += (p0 + p1) + (p2 + p3);
        store_bf16x4(&sPt[wv][s][r][c * 16 + g * 4], p0, p1, p2, p3);
      }
    // O^T += V^T @ P^T
#pragma unroll
    for (int kc2 = 0; kc2 < 2; kc2++) {
      short8 pf[2];
#pragma unroll
      for (int s = 0; s < 2; s++)
        pf[s] = *reinterpret_cast<const short8*>(&sPt[wv][s][r][kc2 * 32 + g * 8]);
#pragma unroll
      for (int dt = 0; dt < 4; dt++) {
        const short8 vf = *reinterpret_cast<const short8*>(&vr[dt * 2 + kc2]);
#pragma unroll
        for (int s = 0; s < 2; s++) oacc[s][dt] = MFMA16(vf, pf[s], oacc[s][dt]);
      }
    }
    // prefetch next V tile (latency covered by next iter's S-phase + exp)
    if (jt + 1 < NJ) {
      const int jo = (jt + 1) * 64;
#pragma unroll
      for (int dt = 0; dt < 4; dt++)
#pragma unroll
        for (int kc2 = 0; kc2 < 2; kc2++)
          vr[dt * 2 + kc2] =
              *reinterpret_cast<const uint4*>(vl + (size_t)(dt * 16) * SEQ + jo + kc2 * 32);
    }
  }
  // fold denominator across the 4 lanes sharing row i=r (lanes l, l^16, l^32, l^48)
#pragma unroll
  for (int s = 0; s < 2; s++) {
    lsum[s] += __shfl_xor(lsum[s], 16);
    lsum[s] += __shfl_xor(lsum[s], 32);
  }
  if (SPLIT) {
    const size_t obase = ((size_t)jh * 32 + bh) * SEQ;
#pragma unroll
    for (int s = 0; s < 2; s++) {
      const int i = i0 + s * 16 + r;
      if (l < 16) lpart[obase + i] = lsum[s];
#pragma unroll
      for (int dt = 0; dt < 4; dt++)
        store_bf16x4(opart + (obase + i) * 64 + dt * 16 + g * 4, oacc[s][dt][0],
                     oacc[s][dt][1], oacc[s][dt][2], oacc[s][dt][3]);
    }
  } else {
#pragma unroll
    for (int s = 0; s < 2; s++) {
      const float inv = 1.0f / lsum[s];
      const int i = i0 + s * 16 + r;
#pragma unroll
      for (int dt = 0; dt < 4; dt++)
        store_bf16x4(ao + ((size_t)(b * SEQ) + i) * DIM + h * DH + dt * 16 + g * 4,
                     oacc[s][dt][0] * inv, oacc[s][dt][1] * inv, oacc[s][dt][2] * inv,
                     oacc[s][dt][3] * inv);
    }
  }
}

// ---------------- Combine the two j-half partials: ao = (o0+o1)/(l0+l1) ----------------
__global__ void attn_combine_kernel(const bf16* __restrict__ opart,
                                    const float* __restrict__ lpart, bf16* __restrict__ ao) {
  const int bh = blockIdx.y, b = bh >> 3, h = bh & 7;
  const int t = threadIdx.x;
  const int i = blockIdx.x * 16 + (t >> 4);
  const int d = (t & 15) * 4;
  const size_t row0 = (size_t)bh * SEQ + i;
  const size_t row1 = ((size_t)32 + bh) * SEQ + i;
  const ushort4 a = *reinterpret_cast<const ushort4*>(opart + row0 * 64 + d);
  const ushort4 c = *reinterpret_cast<const ushort4*>(opart + row1 * 64 + d);
  const float inv = 1.0f / (lpart[row0] + lpart[row1]);
#define B2F(us) __uint_as_float(((unsigned)(us)) << 16)
  store_bf16x4(ao + ((size_t)(b * SEQ) + i) * DIM + h * DH + d,
               (B2F(a.x) + B2F(c.x)) * inv, (B2F(a.y) + B2F(c.y)) * inv,
               (B2F(a.z) + B2F(c.z)) * inv, (B2F(a.w) + B2F(c.w)) * inv);
#undef B2F
}

// ------ Output projection + bias + residual, 128x64 tile, dbuf, fp32 out ------
__launch_bounds__(256, 2)
__global__ void gemm_proj_kernel(const bf16* __restrict__ A, const bf16* __restrict__ Bt,
                                 const float* __restrict__ bo, const float* __restrict__ x,
                                 float* __restrict__ out) {
  const int m0 = blockIdx.x * 128, n0 = blockIdx.y * 64;
  __shared__ __align__(16) bf16 sA[2][128 * 32];
  __shared__ __align__(16) bf16 sB[2][64 * 32];
  const int t = threadIdx.x, w = t >> 6, l = t & 63;
  const int r = l & 15, g = l >> 4;
  const int wm = w >> 1, wn = w & 1;  // wave: rows wm*64.., cols wn*32..
  const int arow = t >> 2;
  const int ccol = (t & 3) * 8;
  const bf16* gA = A + (size_t)(m0 + arow) * DIM + ccol;
  const bf16* gB = Bt + (size_t)(n0 + arow) * DIM + ccol;
  const int loff = t * 8;
  f32x4 acc[4][2] = {};
  glds16(gA, sA[0] + loff);
  glds16(gA + 64 * DIM, sA[0] + loff + 2048);
  glds16(gB, sB[0] + loff);
  const int NK = DIM / 32;
  for (int ks = 0; ks < NK; ks++) {
    const int cur = ks & 1;
    __syncthreads();
    if (ks + 1 < NK) {
      const int k0n = (ks + 1) * 32;
      glds16(gA + k0n, sA[1 - cur] + loff);
      glds16(gA + 64 * DIM + k0n, sA[1 - cur] + loff + 2048);
      glds16(gB + k0n, sB[1 - cur] + loff);
    }
    short8 af[4], bfv[2];
#pragma unroll
    for (int i = 0; i < 4; i++)
      af[i] = *reinterpret_cast<const short8*>(&sA[cur][(wm * 64 + i * 16 + r) * 32 + g * 8]);
#pragma unroll
    for (int j = 0; j < 2; j++)
      bfv[j] = *reinterpret_cast<const short8*>(&sB[cur][(wn * 32 + j * 16 + r) * 32 + g * 8]);
#pragma unroll
    for (int i = 0; i < 4; i++)
#pragma unroll
      for (int j = 0; j < 2; j++) acc[i][j] = MFMA16(af[i], bfv[j], acc[i][j]);
  }
#pragma unroll
  for (int i = 0; i < 4; i++)
#pragma unroll
    for (int j = 0; j < 2; j++)
#pragma unroll
      for (int reg = 0; reg < 4; reg++) {
        const int m = m0 + wm * 64 + i * 16 + g * 4 + reg;
        const int col = n0 + wn * 32 + j * 16 + r;
        out[(size_t)m * DIM + col] = acc[i][j][reg] + bo[col] + x[(size_t)m * DIM + col];
      }
}

extern "C" void kernel_launch(void* const* d_in, const int* in_sizes, int n_in,
                              void* d_out, int out_size, void* d_ws, size_t ws_size,
                              hipStream_t stream) {
  (void)in_sizes; (void)n_in; (void)out_size;
  const float* x    = (const float*)d_in[0];
  const float* ln_g = (const float*)d_in[1];
  const float* ln_b = (const float*)d_in[2];
  const float* Wq   = (const float*)d_in[3];
  const float* Wk   = (const float*)d_in[4];
  const float* Wv   = (const float*)d_in[5];
  const float* Wo   = (const float*)d_in[6];
  const float* bo   = (const float*)d_in[7];
  float* out = (float*)d_out;
  char* ws = (char*)d_ws;
  // ws layout (MB): [0,8) xn | [8,10) wt x4 | [10,18) q | [18,26) k | [26,34) v^T
  //                 [34,42) attn_out | [42,58) opart (split) | [58,58.5) lpart
  bf16* xn  = (bf16*)(ws);
  bf16* wt  = (bf16*)(ws + (8u << 20));
  bf16* qb  = (bf16*)(ws + (10u << 20));
  bf16* kb  = (bf16*)(ws + (18u << 20));
  bf16* vtb = (bf16*)(ws + (26u << 20));
  bf16* aob = (bf16*)(ws + (34u << 20));
  bf16* opart = (bf16*)(ws + (42u << 20));
  float* lpart = (float*)(ws + (58u << 20));
  const bool split = ws_size >= ((58u << 20) + (1u << 19));

  ln_kernel<<<NROWS, 256, 0, stream>>>(x, ln_g, ln_b, xn);
  wt_all_kernel<<<dim3(16, 16, 4), 256, 0, stream>>>(Wq, Wk, Wv, Wo, wt);
  gemm_qkv_kernel<<<dim3(NROWS / 128, (3 * DIM) / 128), 256, 0, stream>>>(xn, wt, qb, kb, vtb);
  if (split) {
    attn_kernel<true><<<dim3(SEQ / 64, BATCH * NHEADS, 2), 128, 0, stream>>>(
        qb, kb, vtb, aob, opart, lpart);
    attn_combine_kernel<<<dim3(SEQ / 16, BATCH * NHEADS), 256, 0, stream>>>(opart, lpart, aob);
  } else {
    attn_kernel<false><<<dim3(SEQ / 64, BATCH * NHEADS, 1), 128, 0, stream>>>(
        qb, kb, vtb, aob, opart, lpart);
  }
  gemm_proj_kernel<<<dim3(NROWS / 128, DIM / 64), 256, 0, stream>>>(aob, wt + 3 * DIM * DIM,
                                                                    bo, x, out);
}

// Round 8
// 230.495 us; speedup vs baseline: 1.0597x; 1.0597x over previous
//
#include <hip/hip_runtime.h>
#include <hip/hip_bf16.h>

#define DIM 512
#define SEQ 2048
#define BATCH 4
#define NHEADS 8
#define DH 64
#define NROWS (BATCH * SEQ)
#define LN_EPS 1e-5f

typedef __hip_bfloat16 bf16;
typedef __attribute__((ext_vector_type(8))) short short8;
typedef __attribute__((ext_vector_type(4))) float f32x4;

#define MFMA16(a, b, c) __builtin_amdgcn_mfma_f32_16x16x32_bf16((a), (b), (c), 0, 0, 0)

#if __has_builtin(__builtin_amdgcn_exp2f)
#define EXP2(x) __builtin_amdgcn_exp2f(x)
#else
#define EXP2(x) exp2f(x)
#endif

#if defined(__has_builtin)
#if __has_builtin(__builtin_amdgcn_global_load_lds)
#define HAS_GLDS 1
#endif
#endif

// async global->LDS, 16B per lane; LDS dest = wave-uniform base + lane*16
__device__ __forceinline__ void glds16(const bf16* g, bf16* l) {
#ifdef HAS_GLDS
  __builtin_amdgcn_global_load_lds((const __attribute__((address_space(1))) void*)g,
                                   (__attribute__((address_space(3))) void*)l, 16, 0, 0);
#else
  *reinterpret_cast<uint4*>(l) = *reinterpret_cast<const uint4*>(g);
#endif
}

__device__ __forceinline__ void store_bf16x4(bf16* p, float a, float b, float c, float d) {
  bf16 tmp[4] = {__float2bfloat16(a), __float2bfloat16(b), __float2bfloat16(c),
                 __float2bfloat16(d)};
  *reinterpret_cast<ushort4*>(p) = *reinterpret_cast<const ushort4*>(tmp);
}

#define B2F(us) __uint_as_float(((unsigned)(us)) << 16)

// scale * log2(e), folded into Wq so attention's softmax is a bare v_exp_f32
#define Q_SCALE_LOG2E 0.06375872f

// -------- Fused setup: LayerNorm (blocks [0,NROWS)) + 4 weight transposes (rest) --------
__global__ void setup_kernel(const float* __restrict__ x, const float* __restrict__ gamma,
                             const float* __restrict__ beta, bf16* __restrict__ xn,
                             const float* __restrict__ Wq, const float* __restrict__ Wk,
                             const float* __restrict__ Wv, const float* __restrict__ Wo,
                             bf16* __restrict__ Wt) {
  __shared__ float red[8];
  __shared__ float stats[2];
  __shared__ float tile[32][33];
  const int t = threadIdx.x;
  if (blockIdx.x < NROWS) {
    // ---- LayerNorm + cast to bf16 (256 thr, 2 elems each) ----
    const int row = blockIdx.x;
    const float2 v = reinterpret_cast<const float2*>(x + (size_t)row * DIM)[t];
    float s = v.x + v.y;
    float ss = v.x * v.x + v.y * v.y;
#pragma unroll
    for (int off = 32; off > 0; off >>= 1) {
      s += __shfl_down(s, off);
      ss += __shfl_down(ss, off);
    }
    if ((t & 63) == 0) { red[(t >> 6) * 2] = s; red[(t >> 6) * 2 + 1] = ss; }
    __syncthreads();
    if (t == 0) {
      float S = red[0] + red[2] + red[4] + red[6];
      float SS = red[1] + red[3] + red[5] + red[7];
      float mu = S * (1.0f / DIM);
      float var = SS * (1.0f / DIM) - mu * mu;
      stats[0] = mu;
      stats[1] = rsqrtf(var + LN_EPS);
    }
    __syncthreads();
    const float mu = stats[0], rs = stats[1];
    const float2 gg = reinterpret_cast<const float2*>(gamma)[t];
    const float2 bb = reinterpret_cast<const float2*>(beta)[t];
    __hip_bfloat162 o;
    o.x = __float2bfloat16((v.x - mu) * rs * gg.x + bb.x);
    o.y = __float2bfloat16((v.y - mu) * rs * gg.y + bb.y);
    reinterpret_cast<__hip_bfloat162*>(xn + (size_t)row * DIM)[t] = o;
  } else {
    // ---- weight transpose + cast + scale: W[K][N] fp32 -> Wt[N][K] bf16 ----
    const int idx = blockIdx.x - NROWS;
    const int bx = idx & 15, by = (idx >> 4) & 15, z = idx >> 8;
    const float* __restrict__ W = (z == 0) ? Wq : (z == 1) ? Wk : (z == 2) ? Wv : Wo;
    const float scale = (z == 0) ? Q_SCALE_LOG2E : 1.0f;
    bf16* __restrict__ dst = Wt + (size_t)z * DIM * DIM;
    const int tx = t & 31, ty = t >> 5;  // 32 x 8
#pragma unroll
    for (int i = 0; i < 32; i += 8)
      tile[ty + i][tx] = W[(size_t)(by * 32 + ty + i) * DIM + bx * 32 + tx];
    __syncthreads();
#pragma unroll
    for (int i = 0; i < 32; i += 8)
      dst[(size_t)(bx * 32 + ty + i) * DIM + by * 32 + tx] =
          __float2bfloat16(tile[tx][ty + i] * scale);
  }
}

// ------ Fused QKV GEMM: C[M,1536] = A[M,512] @ Wt[1536,512]^T, 128x128 tile, dbuf ------
// q,k written [b][n][512]; V written TRANSPOSED [b][512][seq] via LDS-staged epilogue.
__launch_bounds__(256, 3)
__global__ void gemm_qkv_kernel(const bf16* __restrict__ A, const bf16* __restrict__ Bt,
                                bf16* __restrict__ qo, bf16* __restrict__ ko,
                                bf16* __restrict__ vto) {
  const int m0 = blockIdx.x * 128, n0g = blockIdx.y * 128;
  // union: K-loop uses sA/sB dbuf (32 KB); z==2 epilogue reuses as 128x136 transpose tile
  __shared__ __align__(16) char smem[128 * 136 * 2];  // 34816 B
  bf16* const sA = (bf16*)smem;             // [2][128*32]
  bf16* const sB = (bf16*)(smem + 16384);   // [2][128*32]
  bf16* const sT = (bf16*)smem;             // [128][136]
  const int t = threadIdx.x, w = t >> 6, l = t & 63;
  const int r = l & 15, g = l >> 4;
  const int wm = w >> 1, wn = w & 1;
  const int crow = w * 32 + (l >> 2);
  const int ccol = (l & 3) * 8;
  const bf16* gA = A + (size_t)(m0 + crow) * DIM + ccol;
  const bf16* gB = Bt + (size_t)(n0g + crow) * DIM + ccol;
  const int loff = w * 1024 + l * 8;
  f32x4 acc[4][4] = {};
  glds16(gA, sA + loff);
  glds16(gA + 16 * DIM, sA + loff + 512);
  glds16(gB, sB + loff);
  glds16(gB + 16 * DIM, sB + loff + 512);
  const int NK = DIM / 32;
  for (int ks = 0; ks < NK; ks++) {
    const int cur = ks & 1;
    __syncthreads();  // buf[cur] ready (drains vmcnt); all reads of buf[1-cur] done
    if (ks + 1 < NK) {
      const int k0n = (ks + 1) * 32;
      glds16(gA + k0n, sA + (1 - cur) * 4096 + loff);
      glds16(gA + 16 * DIM + k0n, sA + (1 - cur) * 4096 + loff + 512);
      glds16(gB + k0n, sB + (1 - cur) * 4096 + loff);
      glds16(gB + 16 * DIM + k0n, sB + (1 - cur) * 4096 + loff + 512);
    }
    short8 af[4], bfv[4];
#pragma unroll
    for (int i = 0; i < 4; i++)
      af[i] = *reinterpret_cast<const short8*>(
          &sA[cur * 4096 + (wm * 64 + i * 16 + r) * 32 + g * 8]);
#pragma unroll
    for (int j = 0; j < 4; j++)
      bfv[j] = *reinterpret_cast<const short8*>(
          &sB[cur * 4096 + (wn * 64 + j * 16 + r) * 32 + g * 8]);
#pragma unroll
    for (int i = 0; i < 4; i++)
#pragma unroll
      for (int j = 0; j < 4; j++) acc[i][j] = MFMA16(af[i], bfv[j], acc[i][j]);
  }
  const int z = n0g >> 9;  // which of q/k/v this n-tile belongs to
  const int b = m0 / SEQ;  // 128 | SEQ so whole block shares b
  if (z != 2) {
    bf16* __restrict__ outp = (z == 0) ? qo : ko;
    const int nc0 = (n0g & 511) + wn * 64;
#pragma unroll
    for (int i = 0; i < 4; i++)
#pragma unroll
      for (int j = 0; j < 4; j++)
#pragma unroll
        for (int reg = 0; reg < 4; reg++) {
          const int m = m0 + wm * 64 + i * 16 + g * 4 + reg;
          const int col = nc0 + j * 16 + r;
          outp[(size_t)m * DIM + col] = __float2bfloat16(acc[i][j][reg]);
        }
  } else {
    // transpose epilogue: acc -> sT[n][m] -> coalesced V^T writes (16B along seq)
    __syncthreads();  // done with sA/sB
#pragma unroll
    for (int i = 0; i < 4; i++)
#pragma unroll
      for (int j = 0; j < 4; j++)
        store_bf16x4(&sT[(wn * 64 + j * 16 + r) * 136 + wm * 64 + i * 16 + g * 4],
                     acc[i][j][0], acc[i][j][1], acc[i][j][2], acc[i][j][3]);
    __syncthreads();
    const int dr = t >> 1;        // 0..127: d-row within this 128-wide n-tile
    const int mc = (t & 1) * 64;  // m-half
    const int dcol = (n0g & 511) + dr;
    bf16* dst = vto + ((size_t)b * DIM + dcol) * SEQ + (m0 - b * SEQ) + mc;
#pragma unroll
    for (int uu = 0; uu < 8; uu++)
      *reinterpret_cast<uint4*>(dst + uu * 8) =
          *reinterpret_cast<const uint4*>(&sT[dr * 136 + mc + uu * 8]);
  }
}

// ---------------- Flash attention: S^T/O^T form, 16x16x32 MFMA, j-split ----------------
// (R6-proven structure.) block = 128 thr (2 waves), 64 q-rows x one (b,h); wave owns 32
// q-rows (2 strips of 16). S^T = MFMA(K-frag, Q-frag): P^T C-layout has i = lane&15 fixed
// -> scalar denominator, b64 sPt writes; PV: O^T = MFMA(V^T-frag, P^T-frag).
// K/V staged via global_load_lds into XOR-swizzled LDS (16B unit (j,u) at slot j*8+((u+j)&7)).
// sPt stride 78 (odd word-stride 39) spreads b64 writes over all banks (~2-way max).
// SPLIT: grid.z=2 j-halves write unnormalized bf16 partials + per-row sums.
template <bool SPLIT>
__launch_bounds__(128, 3)
__global__ void attn_kernel(const bf16* __restrict__ q, const bf16* __restrict__ k,
                            const bf16* __restrict__ vt, bf16* __restrict__ opart,
                            float* __restrict__ lpart) {
  const int it = blockIdx.x, bh = blockIdx.y, jh = blockIdx.z;
  const int b = bh >> 3, h = bh & 7;
  const int t = threadIdx.x, wv = t >> 6, l = t & 63;
  const int r = l & 15, g = l >> 4;
  __shared__ __align__(16) bf16 sK[64 * 64];
  __shared__ __align__(16) bf16 sV[64 * 64];
  __shared__ __align__(16) bf16 sPt[2][2][16][78];  // [wave][strip][i][j+pad]; wave-private
  const int i0 = it * 64 + wv * 32;
  // Q B-frags: lane holds Q[i = i0+s*16+r][d = kc*32 + g*8 ..+7]
  const bf16* qp = q + ((size_t)(b * SEQ) + i0 + r) * DIM + h * DH;
  short8 qf[2][2];
#pragma unroll
  for (int s = 0; s < 2; s++)
#pragma unroll
    for (int kc = 0; kc < 2; kc++)
      qf[s][kc] = *reinterpret_cast<const short8*>(qp + s * 16 * DIM + kc * 32 + g * 8);
  f32x4 oacc[2][4] = {};       // O^T C-layout: row d = dt*16+g*4+reg, col i = r
  float lsum[2] = {0.f, 0.f};  // denominator partial for row i (fixed per lane)
  const int jbase = SPLIT ? jh * (SEQ / 2) : 0;
  // staging: wave wv stages chunks W = wv*4+cc; lane n -> row n>>3, unit ((n&7)-(n>>3))&7
  const int srow8 = l >> 3;
  const int u = ((l & 7) - srow8) & 7;
  const bf16* kg = k + ((size_t)(b * SEQ) + jbase + wv * 32 + srow8) * DIM + h * DH + u * 8;
  const bf16* vg = vt + ((size_t)(b * DIM) + h * DH + wv * 32 + srow8) * SEQ + jbase + u * 8;
  const int loff = wv * 2048 + l * 8;
  // per-lane swizzled fragment-read offsets (constant across c/dt since c*16 % 8 == 0)
  const int e0 = 64 * r + 8 * ((g + r) & 7);      // k-chunk 0 (units g+0)
  const int e1 = 64 * r + 8 * ((4 + g + r) & 7);  // k-chunk 1 (units g+4)
  const int NJ = SPLIT ? (SEQ / 2) / 64 : SEQ / 64;
  for (int jt = 0; jt < NJ; jt++) {
    const int j0 = jt * 64;
#pragma unroll
    for (int cc = 0; cc < 4; cc++) {
      glds16(kg + (size_t)(j0 + cc * 8) * DIM, sK + loff + cc * 512);
      glds16(vg + (size_t)(cc * 8) * SEQ + j0, sV + loff + cc * 512);
    }
    __syncthreads();
    // S^T = K @ Q^T : A = K-frags (shared across strips), B = Q-frags
    f32x4 st[2][4];
#pragma unroll
    for (int c = 0; c < 4; c++) {
      const short8 kf0 = *reinterpret_cast<const short8*>(sK + 1024 * c + e0);
      const short8 kf1 = *reinterpret_cast<const short8*>(sK + 1024 * c + e1);
#pragma unroll
      for (int s = 0; s < 2; s++) {
        f32x4 a = {0.f, 0.f, 0.f, 0.f};
        a = MFMA16(kf0, qf[s][0], a);
        a = MFMA16(kf1, qf[s][1], a);
        st[s][c] = a;
      }
    }
    // p = exp2(S^T); scalar denominator; b64 P^T writes (4 consecutive j)
#pragma unroll
    for (int s = 0; s < 2; s++)
#pragma unroll
      for (int c = 0; c < 4; c++) {
        const float p0 = EXP2(st[s][c][0]);
        const float p1 = EXP2(st[s][c][1]);
        const float p2 = EXP2(st[s][c][2]);
        const float p3 = EXP2(st[s][c][3]);
        lsum[s] += (p0 + p1) + (p2 + p3);
        store_bf16x4(&sPt[wv][s][r][c * 16 + g * 4], p0, p1, p2, p3);
      }
    // O^T += V^T @ P^T
#pragma unroll
    for (int kc2 = 0; kc2 < 2; kc2++) {
      short8 pf[2];
#pragma unroll
      for (int s = 0; s < 2; s++)
        pf[s] = *reinterpret_cast<const short8*>(&sPt[wv][s][r][kc2 * 32 + g * 8]);
      const int ev = (kc2 == 0) ? e0 : e1;
#pragma unroll
      for (int dt = 0; dt < 4; dt++) {
        const short8 vf = *reinterpret_cast<const short8*>(sV + 1024 * dt + ev);
#pragma unroll
        for (int s = 0; s < 2; s++) oacc[s][dt] = MFMA16(vf, pf[s], oacc[s][dt]);
      }
    }
    __syncthreads();  // WAR guard before next glds overwrite
  }
  // fold denominator across the 4 lanes sharing row i=r (lanes l, l^16, l^32, l^48)
#pragma unroll
  for (int s = 0; s < 2; s++) {
    lsum[s] += __shfl_xor(lsum[s], 16);
    lsum[s] += __shfl_xor(lsum[s], 32);
  }
  // write unnormalized partials + row sums (proj kernel fuses the combine+normalize)
  const size_t obase = ((size_t)(SPLIT ? jh * 32 : 0) + bh) * SEQ;
#pragma unroll
  for (int s = 0; s < 2; s++) {
    const int i = i0 + s * 16 + r;
    if (l < 16) lpart[obase + i] = lsum[s];
#pragma unroll
    for (int dt = 0; dt < 4; dt++)
      store_bf16x4(opart + (obase + i) * 64 + dt * 16 + g * 4, oacc[s][dt][0], oacc[s][dt][1],
                   oacc[s][dt][2], oacc[s][dt][3]);
  }
  if (!SPLIT) {  // fallback: zero the second-half partials so the fused combine is a no-op add
    const size_t obase1 = ((size_t)32 + bh) * SEQ;
#pragma unroll
    for (int s = 0; s < 2; s++) {
      const int i = i0 + s * 16 + r;
      if (l < 16) lpart[obase1 + i] = 0.f;
#pragma unroll
      for (int dt = 0; dt < 4; dt++)
        store_bf16x4(opart + (obase1 + i) * 64 + dt * 16 + g * 4, 0.f, 0.f, 0.f, 0.f);
    }
  }
}

// ------ Output projection + FUSED attn-combine + bias + residual, 128x64 tile, fp32 out ------
// A[m][k] = (opart0 + opart1)[bh(m,k)][i(m)][d(k)] / (lpart0 + lpart1), staged to LDS in regs.
__launch_bounds__(256, 2)
__global__ void gemm_proj_kernel(const bf16* __restrict__ opart, const float* __restrict__ lpart,
                                 const bf16* __restrict__ Bt, const float* __restrict__ bo,
                                 const float* __restrict__ x, float* __restrict__ out) {
  const int m0 = blockIdx.x * 128, n0 = blockIdx.y * 64;
  __shared__ __align__(16) bf16 sA[128 * 32];
  __shared__ __align__(16) bf16 sB[64 * 32];
  const int t = threadIdx.x, w = t >> 6, l = t & 63;
  const int r = l & 15, g = l >> 4;
  const int wm = w >> 1, wn = w & 1;  // wave: rows wm*64.., cols wn*32..
  // staging coords: A chunks c=0,1: row c*64 + (t>>2), col (t&3)*8; B: row t>>2, col (t&3)*8
  const int arow = t >> 2;
  const int acol = (t & 3) * 8;
  const int b = (m0 + arow) >> 11;          // batch (tile rows share high bits except arow)
  const int i_lo = (m0 + arow) & 2047;      // seq index for chunk 0 row
  const bf16* gB = Bt + (size_t)(n0 + arow) * DIM + acol;
  f32x4 acc[4][2] = {};
  const int NK = DIM / 32;
  for (int ks = 0; ks < NK; ks++) {
    const int k0 = ks * 32;
    const int h = k0 >> 6;                  // head for this whole k-step
    const int d0 = (k0 & 63) + acol;        // d within head
    // A combine-load into regs (2 chunks of 64 rows)
    uint4 areg[2];
#pragma unroll
    for (int c = 0; c < 2; c++) {
      const int m = m0 + c * 64 + arow;
      const int bb = m >> 11, ii = m & 2047;
      const size_t row0 = ((size_t)(bb * 8 + h)) * SEQ + ii;
      const size_t row1 = row0 + (size_t)32 * SEQ;
      const uint4 A0 = *reinterpret_cast<const uint4*>(opart + row0 * 64 + d0);
      const uint4 A1 = *reinterpret_cast<const uint4*>(opart + row1 * 64 + d0);
      const float inv = 1.0f / (lpart[row0] + lpart[row1]);
      const ushort* a0 = (const ushort*)&A0;
      const ushort* a1 = (const ushort*)&A1;
      bf16 rr[8];
#pragma unroll
      for (int e = 0; e < 8; e++)
        rr[e] = __float2bfloat16((B2F(a0[e]) + B2F(a1[e])) * inv);
      areg[c] = *reinterpret_cast<const uint4*>(rr);
    }
    const uint4 breg = *reinterpret_cast<const uint4*>(gB + k0);
    __syncthreads();  // all frag reads of previous tile done (WAR)
    *reinterpret_cast<uint4*>(&sA[(0 * 64 + arow) * 32 + acol]) = areg[0];
    *reinterpret_cast<uint4*>(&sA[(1 * 64 + arow) * 32 + acol]) = areg[1];
    *reinterpret_cast<uint4*>(&sB[arow * 32 + acol]) = breg;
    __syncthreads();  // writes visible
    short8 af[4], bfv[2];
#pragma unroll
    for (int i = 0; i < 4; i++)
      af[i] = *reinterpret_cast<const short8*>(&sA[(wm * 64 + i * 16 + r) * 32 + g * 8]);
#pragma unroll
    for (int j = 0; j < 2; j++)
      bfv[j] = *reinterpret_cast<const short8*>(&sB[(wn * 32 + j * 16 + r) * 32 + g * 8]);
#pragma unroll
    for (int i = 0; i < 4; i++)
#pragma unroll
      for (int j = 0; j < 2; j++) acc[i][j] = MFMA16(af[i], bfv[j], acc[i][j]);
  }
  (void)b; (void)i_lo;
#pragma unroll
  for (int i = 0; i < 4; i++)
#pragma unroll
    for (int j = 0; j < 2; j++)
#pragma unroll
      for (int reg = 0; reg < 4; reg++) {
        const int m = m0 + wm * 64 + i * 16 + g * 4 + reg;
        const int col = n0 + wn * 32 + j * 16 + r;
        out[(size_t)m * DIM + col] = acc[i][j][reg] + bo[col] + x[(size_t)m * DIM + col];
      }
}

extern "C" void kernel_launch(void* const* d_in, const int* in_sizes, int n_in,
                              void* d_out, int out_size, void* d_ws, size_t ws_size,
                              hipStream_t stream) {
  (void)in_sizes; (void)n_in; (void)out_size;
  const float* x    = (const float*)d_in[0];
  const float* ln_g = (const float*)d_in[1];
  const float* ln_b = (const float*)d_in[2];
  const float* Wq   = (const float*)d_in[3];
  const float* Wk   = (const float*)d_in[4];
  const float* Wv   = (const float*)d_in[5];
  const float* Wo   = (const float*)d_in[6];
  const float* bo   = (const float*)d_in[7];
  float* out = (float*)d_out;
  char* ws = (char*)d_ws;
  // ws layout (MB): [0,8) xn | [8,10) wt x4 | [10,18) q | [18,26) k | [26,34) v^T
  //                 [34,50) opart (2 j-halves, bf16, unnormalized) | [50,50.5) lpart
  bf16* xn  = (bf16*)(ws);
  bf16* wt  = (bf16*)(ws + (8u << 20));
  bf16* qb  = (bf16*)(ws + (10u << 20));
  bf16* kb  = (bf16*)(ws + (18u << 20));
  bf16* vtb = (bf16*)(ws + (26u << 20));
  bf16* opart = (bf16*)(ws + (34u << 20));
  float* lpart = (float*)(ws + (50u << 20));
  const bool split = ws_size >= ((50u << 20) + (1u << 19));

  setup_kernel<<<NROWS + 1024, 256, 0, stream>>>(x, ln_g, ln_b, xn, Wq, Wk, Wv, Wo, wt);
  gemm_qkv_kernel<<<dim3(NROWS / 128, (3 * DIM) / 128), 256, 0, stream>>>(xn, wt, qb, kb, vtb);
  if (split) {
    attn_kernel<true><<<dim3(SEQ / 64, BATCH * NHEADS, 2), 128, 0, stream>>>(
        qb, kb, vtb, opart, lpart);
  } else {
    attn_kernel<false><<<dim3(SEQ / 64, BATCH * NHEADS, 1), 128, 0, stream>>>(
        qb, kb, vtb, opart, lpart);
  }
  gemm_proj_kernel<<<dim3(NROWS / 128, DIM / 64), 256, 0, stream>>>(
      opart, lpart, wt + 3 * DIM * DIM, bo, x, out);
}

// Round 9
// 179.698 us; speedup vs baseline: 1.3592x; 1.2827x over previous
//
#include <hip/hip_runtime.h>
#include <hip/hip_bf16.h>

#define DIM 512
#define SEQ 2048
#define BATCH 4
#define NHEADS 8
#define DH 64
#define NROWS (BATCH * SEQ)
#define LN_EPS 1e-5f

typedef __hip_bfloat16 bf16;
typedef __attribute__((ext_vector_type(8))) short short8;
typedef __attribute__((ext_vector_type(4))) float f32x4;

#define MFMA16(a, b, c) __builtin_amdgcn_mfma_f32_16x16x32_bf16((a), (b), (c), 0, 0, 0)

#if __has_builtin(__builtin_amdgcn_exp2f)
#define EXP2(x) __builtin_amdgcn_exp2f(x)
#else
#define EXP2(x) exp2f(x)
#endif

#if defined(__has_builtin)
#if __has_builtin(__builtin_amdgcn_global_load_lds)
#define HAS_GLDS 1
#endif
#endif

// async global->LDS, 16B per lane; LDS dest = wave-uniform base + lane*16
__device__ __forceinline__ void glds16(const bf16* g, bf16* l) {
#ifdef HAS_GLDS
  __builtin_amdgcn_global_load_lds((const __attribute__((address_space(1))) void*)g,
                                   (__attribute__((address_space(3))) void*)l, 16, 0, 0);
#else
  *reinterpret_cast<uint4*>(l) = *reinterpret_cast<const uint4*>(g);
#endif
}

__device__ __forceinline__ void store_bf16x4(bf16* p, float a, float b, float c, float d) {
  bf16 tmp[4] = {__float2bfloat16(a), __float2bfloat16(b), __float2bfloat16(c),
                 __float2bfloat16(d)};
  *reinterpret_cast<ushort4*>(p) = *reinterpret_cast<const ushort4*>(tmp);
}

#define B2F(us) __uint_as_float(((unsigned)(us)) << 16)

// scale * log2(e), folded into Wq so attention's softmax is a bare v_exp_f32
#define Q_SCALE_LOG2E 0.06375872f

// -------- Fused setup: LayerNorm (blocks [0,NROWS)) + 4 weight transposes (rest) --------
__global__ void setup_kernel(const float* __restrict__ x, const float* __restrict__ gamma,
                             const float* __restrict__ beta, bf16* __restrict__ xn,
                             const float* __restrict__ Wq, const float* __restrict__ Wk,
                             const float* __restrict__ Wv, const float* __restrict__ Wo,
                             bf16* __restrict__ Wt) {
  __shared__ float red[8];
  __shared__ float stats[2];
  __shared__ float tile[32][33];
  const int t = threadIdx.x;
  if (blockIdx.x < NROWS) {
    // ---- LayerNorm + cast to bf16 (256 thr, 2 elems each) ----
    const int row = blockIdx.x;
    const float2 v = reinterpret_cast<const float2*>(x + (size_t)row * DIM)[t];
    float s = v.x + v.y;
    float ss = v.x * v.x + v.y * v.y;
#pragma unroll
    for (int off = 32; off > 0; off >>= 1) {
      s += __shfl_down(s, off);
      ss += __shfl_down(ss, off);
    }
    if ((t & 63) == 0) { red[(t >> 6) * 2] = s; red[(t >> 6) * 2 + 1] = ss; }
    __syncthreads();
    if (t == 0) {
      float S = red[0] + red[2] + red[4] + red[6];
      float SS = red[1] + red[3] + red[5] + red[7];
      float mu = S * (1.0f / DIM);
      float var = SS * (1.0f / DIM) - mu * mu;
      stats[0] = mu;
      stats[1] = rsqrtf(var + LN_EPS);
    }
    __syncthreads();
    const float mu = stats[0], rs = stats[1];
    const float2 gg = reinterpret_cast<const float2*>(gamma)[t];
    const float2 bb = reinterpret_cast<const float2*>(beta)[t];
    __hip_bfloat162 o;
    o.x = __float2bfloat16((v.x - mu) * rs * gg.x + bb.x);
    o.y = __float2bfloat16((v.y - mu) * rs * gg.y + bb.y);
    reinterpret_cast<__hip_bfloat162*>(xn + (size_t)row * DIM)[t] = o;
  } else {
    // ---- weight transpose + cast + scale: W[K][N] fp32 -> Wt[N][K] bf16 ----
    const int idx = blockIdx.x - NROWS;
    const int bx = idx & 15, by = (idx >> 4) & 15, z = idx >> 8;
    const float* __restrict__ W = (z == 0) ? Wq : (z == 1) ? Wk : (z == 2) ? Wv : Wo;
    const float scale = (z == 0) ? Q_SCALE_LOG2E : 1.0f;
    bf16* __restrict__ dst = Wt + (size_t)z * DIM * DIM;
    const int tx = t & 31, ty = t >> 5;  // 32 x 8
#pragma unroll
    for (int i = 0; i < 32; i += 8)
      tile[ty + i][tx] = W[(size_t)(by * 32 + ty + i) * DIM + bx * 32 + tx];
    __syncthreads();
#pragma unroll
    for (int i = 0; i < 32; i += 8)
      dst[(size_t)(bx * 32 + ty + i) * DIM + by * 32 + tx] =
          __float2bfloat16(tile[tx][ty + i] * scale);
  }
}

// ------ Fused QKV GEMM: C[M,1536] = A[M,512] @ Wt[1536,512]^T, 128x128 tile, dbuf ------
// q,k written [b][n][512]; V written TRANSPOSED [b][512][seq] via LDS-staged epilogue.
__launch_bounds__(256, 3)
__global__ void gemm_qkv_kernel(const bf16* __restrict__ A, const bf16* __restrict__ Bt,
                                bf16* __restrict__ qo, bf16* __restrict__ ko,
                                bf16* __restrict__ vto) {
  const int m0 = blockIdx.x * 128, n0g = blockIdx.y * 128;
  // union: K-loop uses sA/sB dbuf (32 KB); z==2 epilogue reuses as 128x136 transpose tile
  __shared__ __align__(16) char smem[128 * 136 * 2];  // 34816 B
  bf16* const sA = (bf16*)smem;             // [2][128*32]
  bf16* const sB = (bf16*)(smem + 16384);   // [2][128*32]
  bf16* const sT = (bf16*)smem;             // [128][136]
  const int t = threadIdx.x, w = t >> 6, l = t & 63;
  const int r = l & 15, g = l >> 4;
  const int wm = w >> 1, wn = w & 1;
  const int crow = w * 32 + (l >> 2);
  const int ccol = (l & 3) * 8;
  const bf16* gA = A + (size_t)(m0 + crow) * DIM + ccol;
  const bf16* gB = Bt + (size_t)(n0g + crow) * DIM + ccol;
  const int loff = w * 1024 + l * 8;
  f32x4 acc[4][4] = {};
  glds16(gA, sA + loff);
  glds16(gA + 16 * DIM, sA + loff + 512);
  glds16(gB, sB + loff);
  glds16(gB + 16 * DIM, sB + loff + 512);
  const int NK = DIM / 32;
  for (int ks = 0; ks < NK; ks++) {
    const int cur = ks & 1;
    __syncthreads();  // buf[cur] ready (drains vmcnt); all reads of buf[1-cur] done
    if (ks + 1 < NK) {
      const int k0n = (ks + 1) * 32;
      glds16(gA + k0n, sA + (1 - cur) * 4096 + loff);
      glds16(gA + 16 * DIM + k0n, sA + (1 - cur) * 4096 + loff + 512);
      glds16(gB + k0n, sB + (1 - cur) * 4096 + loff);
      glds16(gB + 16 * DIM + k0n, sB + (1 - cur) * 4096 + loff + 512);
    }
    short8 af[4], bfv[4];
#pragma unroll
    for (int i = 0; i < 4; i++)
      af[i] = *reinterpret_cast<const short8*>(
          &sA[cur * 4096 + (wm * 64 + i * 16 + r) * 32 + g * 8]);
#pragma unroll
    for (int j = 0; j < 4; j++)
      bfv[j] = *reinterpret_cast<const short8*>(
          &sB[cur * 4096 + (wn * 64 + j * 16 + r) * 32 + g * 8]);
#pragma unroll
    for (int i = 0; i < 4; i++)
#pragma unroll
      for (int j = 0; j < 4; j++) acc[i][j] = MFMA16(af[i], bfv[j], acc[i][j]);
  }
  const int z = n0g >> 9;  // which of q/k/v this n-tile belongs to
  const int b = m0 / SEQ;  // 128 | SEQ so whole block shares b
  if (z != 2) {
    bf16* __restrict__ outp = (z == 0) ? qo : ko;
    const int nc0 = (n0g & 511) + wn * 64;
#pragma unroll
    for (int i = 0; i < 4; i++)
#pragma unroll
      for (int j = 0; j < 4; j++)
#pragma unroll
        for (int reg = 0; reg < 4; reg++) {
          const int m = m0 + wm * 64 + i * 16 + g * 4 + reg;
          const int col = nc0 + j * 16 + r;
          outp[(size_t)m * DIM + col] = __float2bfloat16(acc[i][j][reg]);
        }
  } else {
    // transpose epilogue: acc -> sT[n][m] -> coalesced V^T writes (16B along seq)
    __syncthreads();  // done with sA/sB
#pragma unroll
    for (int i = 0; i < 4; i++)
#pragma unroll
      for (int j = 0; j < 4; j++)
        store_bf16x4(&sT[(wn * 64 + j * 16 + r) * 136 + wm * 64 + i * 16 + g * 4],
                     acc[i][j][0], acc[i][j][1], acc[i][j][2], acc[i][j][3]);
    __syncthreads();
    const int dr = t >> 1;        // 0..127: d-row within this 128-wide n-tile
    const int mc = (t & 1) * 64;  // m-half
    const int dcol = (n0g & 511) + dr;
    bf16* dst = vto + ((size_t)b * DIM + dcol) * SEQ + (m0 - b * SEQ) + mc;
#pragma unroll
    for (int uu = 0; uu < 8; uu++)
      *reinterpret_cast<uint4*>(dst + uu * 8) =
          *reinterpret_cast<const uint4*>(&sT[dr * 136 + mc + uu * 8]);
  }
}

// ---------------- Flash attention: S^T/O^T form, 16x16x32 MFMA, j-split ----------------
// (R6-proven 65 µs configuration — sPt stride 72 restored; this is the single variable
// changed vs R8.) block = 128 thr (2 waves), 64 q-rows x one (b,h); wave owns 32 q-rows
// (2 strips of 16). S^T = MFMA(K-frag, Q-frag): P^T C-layout has i = lane&15 fixed
// -> scalar denominator, b64 sPt writes; PV: O^T = MFMA(V^T-frag, P^T-frag).
// K/V staged via global_load_lds into XOR-swizzled LDS (16B unit (j,u) at slot j*8+((u+j)&7)).
// SPLIT: grid.z=2 j-halves write unnormalized bf16 partials + per-row sums.
template <bool SPLIT>
__launch_bounds__(128, 3)
__global__ void attn_kernel(const bf16* __restrict__ q, const bf16* __restrict__ k,
                            const bf16* __restrict__ vt, bf16* __restrict__ opart,
                            float* __restrict__ lpart) {
  const int it = blockIdx.x, bh = blockIdx.y, jh = blockIdx.z;
  const int b = bh >> 3, h = bh & 7;
  const int t = threadIdx.x, wv = t >> 6, l = t & 63;
  const int r = l & 15, g = l >> 4;
  __shared__ __align__(16) bf16 sK[64 * 64];
  __shared__ __align__(16) bf16 sV[64 * 64];
  __shared__ __align__(16) bf16 sPt[2][2][16][72];  // [wave][strip][i][j+pad]; wave-private
  const int i0 = it * 64 + wv * 32;
  // Q B-frags: lane holds Q[i = i0+s*16+r][d = kc*32 + g*8 ..+7]
  const bf16* qp = q + ((size_t)(b * SEQ) + i0 + r) * DIM + h * DH;
  short8 qf[2][2];
#pragma unroll
  for (int s = 0; s < 2; s++)
#pragma unroll
    for (int kc = 0; kc < 2; kc++)
      qf[s][kc] = *reinterpret_cast<const short8*>(qp + s * 16 * DIM + kc * 32 + g * 8);
  f32x4 oacc[2][4] = {};       // O^T C-layout: row d = dt*16+g*4+reg, col i = r
  float lsum[2] = {0.f, 0.f};  // denominator partial for row i (fixed per lane)
  const int jbase = SPLIT ? jh * (SEQ / 2) : 0;
  // staging: wave wv stages chunks W = wv*4+cc; lane n -> row n>>3, unit ((n&7)-(n>>3))&7
  const int srow8 = l >> 3;
  const int u = ((l & 7) - srow8) & 7;
  const bf16* kg = k + ((size_t)(b * SEQ) + jbase + wv * 32 + srow8) * DIM + h * DH + u * 8;
  const bf16* vg = vt + ((size_t)(b * DIM) + h * DH + wv * 32 + srow8) * SEQ + jbase + u * 8;
  const int loff = wv * 2048 + l * 8;
  // per-lane swizzled fragment-read offsets (constant across c/dt since c*16 % 8 == 0)
  const int e0 = 64 * r + 8 * ((g + r) & 7);      // k-chunk 0 (units g+0)
  const int e1 = 64 * r + 8 * ((4 + g + r) & 7);  // k-chunk 1 (units g+4)
  const int NJ = SPLIT ? (SEQ / 2) / 64 : SEQ / 64;
  for (int jt = 0; jt < NJ; jt++) {
    const int j0 = jt * 64;
#pragma unroll
    for (int cc = 0; cc < 4; cc++) {
      glds16(kg + (size_t)(j0 + cc * 8) * DIM, sK + loff + cc * 512);
      glds16(vg + (size_t)(cc * 8) * SEQ + j0, sV + loff + cc * 512);
    }
    __syncthreads();
    // S^T = K @ Q^T : A = K-frags (shared across strips), B = Q-frags
    f32x4 st[2][4];
#pragma unroll
    for (int c = 0; c < 4; c++) {
      const short8 kf0 = *reinterpret_cast<const short8*>(sK + 1024 * c + e0);
      const short8 kf1 = *reinterpret_cast<const short8*>(sK + 1024 * c + e1);
#pragma unroll
      for (int s = 0; s < 2; s++) {
        f32x4 a = {0.f, 0.f, 0.f, 0.f};
        a = MFMA16(kf0, qf[s][0], a);
        a = MFMA16(kf1, qf[s][1], a);
        st[s][c] = a;
      }
    }
    // p = exp2(S^T); scalar denominator; b64 P^T writes (4 consecutive j)
#pragma unroll
    for (int s = 0; s < 2; s++)
#pragma unroll
      for (int c = 0; c < 4; c++) {
        const float p0 = EXP2(st[s][c][0]);
        const float p1 = EXP2(st[s][c][1]);
        const float p2 = EXP2(st[s][c][2]);
        const float p3 = EXP2(st[s][c][3]);
        lsum[s] += (p0 + p1) + (p2 + p3);
        store_bf16x4(&sPt[wv][s][r][c * 16 + g * 4], p0, p1, p2, p3);
      }
    // O^T += V^T @ P^T
#pragma unroll
    for (int kc2 = 0; kc2 < 2; kc2++) {
      short8 pf[2];
#pragma unroll
      for (int s = 0; s < 2; s++)
        pf[s] = *reinterpret_cast<const short8*>(&sPt[wv][s][r][kc2 * 32 + g * 8]);
      const int ev = (kc2 == 0) ? e0 : e1;
#pragma unroll
      for (int dt = 0; dt < 4; dt++) {
        const short8 vf = *reinterpret_cast<const short8*>(sV + 1024 * dt + ev);
#pragma unroll
        for (int s = 0; s < 2; s++) oacc[s][dt] = MFMA16(vf, pf[s], oacc[s][dt]);
      }
    }
    __syncthreads();  // WAR guard before next glds overwrite
  }
  // fold denominator across the 4 lanes sharing row i=r (lanes l, l^16, l^32, l^48)
#pragma unroll
  for (int s = 0; s < 2; s++) {
    lsum[s] += __shfl_xor(lsum[s], 16);
    lsum[s] += __shfl_xor(lsum[s], 32);
  }
  // write unnormalized partials + row sums (proj kernel fuses the combine+normalize)
  const size_t obase = ((size_t)(SPLIT ? jh * 32 : 0) + bh) * SEQ;
#pragma unroll
  for (int s = 0; s < 2; s++) {
    const int i = i0 + s * 16 + r;
    if (l < 16) lpart[obase + i] = lsum[s];
#pragma unroll
    for (int dt = 0; dt < 4; dt++)
      store_bf16x4(opart + (obase + i) * 64 + dt * 16 + g * 4, oacc[s][dt][0], oacc[s][dt][1],
                   oacc[s][dt][2], oacc[s][dt][3]);
  }
  if (!SPLIT) {  // fallback: zero the second-half partials so the fused combine is a no-op add
    const size_t obase1 = ((size_t)32 + bh) * SEQ;
#pragma unroll
    for (int s = 0; s < 2; s++) {
      const int i = i0 + s * 16 + r;
      if (l < 16) lpart[obase1 + i] = 0.f;
#pragma unroll
      for (int dt = 0; dt < 4; dt++)
        store_bf16x4(opart + (obase1 + i) * 64 + dt * 16 + g * 4, 0.f, 0.f, 0.f, 0.f);
    }
  }
}

// ------ Output projection + FUSED attn-combine + bias + residual, 128x64 tile, fp32 out ------
// A[m][k] = (opart0 + opart1)[bh(m,k)][i(m)][d(k)] / (lpart0 + lpart1), staged to LDS in regs.
__launch_bounds__(256, 2)
__global__ void gemm_proj_kernel(const bf16* __restrict__ opart, const float* __restrict__ lpart,
                                 const bf16* __restrict__ Bt, const float* __restrict__ bo,
                                 const float* __restrict__ x, float* __restrict__ out) {
  const int m0 = blockIdx.x * 128, n0 = blockIdx.y * 64;
  __shared__ __align__(16) bf16 sA[128 * 32];
  __shared__ __align__(16) bf16 sB[64 * 32];
  const int t = threadIdx.x, w = t >> 6, l = t & 63;
  const int r = l & 15, g = l >> 4;
  const int wm = w >> 1, wn = w & 1;  // wave: rows wm*64.., cols wn*32..
  const int arow = t >> 2;
  const int acol = (t & 3) * 8;
  const bf16* gB = Bt + (size_t)(n0 + arow) * DIM + acol;
  f32x4 acc[4][2] = {};
  const int NK = DIM / 32;
  for (int ks = 0; ks < NK; ks++) {
    const int k0 = ks * 32;
    const int h = k0 >> 6;            // head for this whole k-step
    const int d0 = (k0 & 63) + acol;  // d within head
    // A combine-load into regs (2 chunks of 64 rows)
    uint4 areg[2];
#pragma unroll
    for (int c = 0; c < 2; c++) {
      const int m = m0 + c * 64 + arow;
      const int bb = m >> 11, ii = m & 2047;
      const size_t row0 = ((size_t)(bb * 8 + h)) * SEQ + ii;
      const size_t row1 = row0 + (size_t)32 * SEQ;
      const uint4 A0 = *reinterpret_cast<const uint4*>(opart + row0 * 64 + d0);
      const uint4 A1 = *reinterpret_cast<const uint4*>(opart + row1 * 64 + d0);
      const float inv = 1.0f / (lpart[row0] + lpart[row1]);
      const ushort* a0 = (const ushort*)&A0;
      const ushort* a1 = (const ushort*)&A1;
      bf16 rr[8];
#pragma unroll
      for (int e = 0; e < 8; e++)
        rr[e] = __float2bfloat16((B2F(a0[e]) + B2F(a1[e])) * inv);
      areg[c] = *reinterpret_cast<const uint4*>(rr);
    }
    const uint4 breg = *reinterpret_cast<const uint4*>(gB + k0);
    __syncthreads();  // all frag reads of previous tile done (WAR)
    *reinterpret_cast<uint4*>(&sA[(0 * 64 + arow) * 32 + acol]) = areg[0];
    *reinterpret_cast<uint4*>(&sA[(1 * 64 + arow) * 32 + acol]) = areg[1];
    *reinterpret_cast<uint4*>(&sB[arow * 32 + acol]) = breg;
    __syncthreads();  // writes visible
    short8 af[4], bfv[2];
#pragma unroll
    for (int i = 0; i < 4; i++)
      af[i] = *reinterpret_cast<const short8*>(&sA[(wm * 64 + i * 16 + r) * 32 + g * 8]);
#pragma unroll
    for (int j = 0; j < 2; j++)
      bfv[j] = *reinterpret_cast<const short8*>(&sB[(wn * 32 + j * 16 + r) * 32 + g * 8]);
#pragma unroll
    for (int i = 0; i < 4; i++)
#pragma unroll
      for (int j = 0; j < 2; j++) acc[i][j] = MFMA16(af[i], bfv[j], acc[i][j]);
  }
#pragma unroll
  for (int i = 0; i < 4; i++)
#pragma unroll
    for (int j = 0; j < 2; j++)
#pragma unroll
      for (int reg = 0; reg < 4; reg++) {
        const int m = m0 + wm * 64 + i * 16 + g * 4 + reg;
        const int col = n0 + wn * 32 + j * 16 + r;
        out[(size_t)m * DIM + col] = acc[i][j][reg] + bo[col] + x[(size_t)m * DIM + col];
      }
}

extern "C" void kernel_launch(void* const* d_in, const int* in_sizes, int n_in,
                              void* d_out, int out_size, void* d_ws, size_t ws_size,
                              hipStream_t stream) {
  (void)in_sizes; (void)n_in; (void)out_size;
  const float* x    = (const float*)d_in[0];
  const float* ln_g = (const float*)d_in[1];
  const float* ln_b = (const float*)d_in[2];
  const float* Wq   = (const float*)d_in[3];
  const float* Wk   = (const float*)d_in[4];
  const float* Wv   = (const float*)d_in[5];
  const float* Wo   = (const float*)d_in[6];
  const float* bo   = (const float*)d_in[7];
  float* out = (float*)d_out;
  char* ws = (char*)d_ws;
  // ws layout (MB): [0,8) xn | [8,10) wt x4 | [10,18) q | [18,26) k | [26,34) v^T
  //                 [34,50) opart (2 j-halves, bf16, unnormalized) | [50,50.5) lpart
  bf16* xn  = (bf16*)(ws);
  bf16* wt  = (bf16*)(ws + (8u << 20));
  bf16* qb  = (bf16*)(ws + (10u << 20));
  bf16* kb  = (bf16*)(ws + (18u << 20));
  bf16* vtb = (bf16*)(ws + (26u << 20));
  bf16* opart = (bf16*)(ws + (34u << 20));
  float* lpart = (float*)(ws + (50u << 20));
  const bool split = ws_size >= ((50u << 20) + (1u << 19));

  setup_kernel<<<NROWS + 1024, 256, 0, stream>>>(x, ln_g, ln_b, xn, Wq, Wk, Wv, Wo, wt);
  gemm_qkv_kernel<<<dim3(NROWS / 128, (3 * DIM) / 128), 256, 0, stream>>>(xn, wt, qb, kb, vtb);
  if (split) {
    attn_kernel<true><<<dim3(SEQ / 64, BATCH * NHEADS, 2), 128, 0, stream>>>(
        qb, kb, vtb, opart, lpart);
  } else {
    attn_kernel<false><<<dim3(SEQ / 64, BATCH * NHEADS, 1), 128, 0, stream>>>(
        qb, kb, vtb, opart, lpart);
  }
  gemm_proj_kernel<<<dim3(NROWS / 128, DIM / 64), 256, 0, stream>>>(
      opart, lpart, wt + 3 * DIM * DIM, bo, x, out);
}

// Round 10
// 165.311 us; speedup vs baseline: 1.4775x; 1.0870x over previous
//
#include <hip/hip_runtime.h>
#include <hip/hip_bf16.h>

#define DIM 512
#define SEQ 2048
#define BATCH 4
#define NHEADS 8
#define DH 64
#define NROWS (BATCH * SEQ)
#define LN_EPS 1e-5f

typedef __hip_bfloat16 bf16;
typedef __attribute__((ext_vector_type(8))) short short8;
typedef __attribute__((ext_vector_type(4))) float f32x4;

#define MFMA16(a, b, c) __builtin_amdgcn_mfma_f32_16x16x32_bf16((a), (b), (c), 0, 0, 0)

#if __has_builtin(__builtin_amdgcn_exp2f)
#define EXP2(x) __builtin_amdgcn_exp2f(x)
#else
#define EXP2(x) exp2f(x)
#endif

#if defined(__has_builtin)
#if __has_builtin(__builtin_amdgcn_global_load_lds)
#define HAS_GLDS 1
#endif
#endif

// async global->LDS, 16B per lane; LDS dest = wave-uniform base + lane*16
__device__ __forceinline__ void glds16(const bf16* g, bf16* l) {
#ifdef HAS_GLDS
  __builtin_amdgcn_global_load_lds((const __attribute__((address_space(1))) void*)g,
                                   (__attribute__((address_space(3))) void*)l, 16, 0, 0);
#else
  *reinterpret_cast<uint4*>(l) = *reinterpret_cast<const uint4*>(g);
#endif
}

__device__ __forceinline__ void store_bf16x4(bf16* p, float a, float b, float c, float d) {
  bf16 tmp[4] = {__float2bfloat16(a), __float2bfloat16(b), __float2bfloat16(c),
                 __float2bfloat16(d)};
  *reinterpret_cast<ushort4*>(p) = *reinterpret_cast<const ushort4*>(tmp);
}

#define B2F(us) __uint_as_float(((unsigned)(us)) << 16)

// scale * log2(e), folded into Wq so attention's softmax is a bare v_exp_f32
#define Q_SCALE_LOG2E 0.06375872f

// -------- Fused setup: LayerNorm wave-per-row (blocks [0,NROWS/4)) + weight transposes --------
__global__ void setup_kernel(const float* __restrict__ x, const float* __restrict__ gamma,
                             const float* __restrict__ beta, bf16* __restrict__ xn,
                             const float* __restrict__ Wq, const float* __restrict__ Wk,
                             const float* __restrict__ Wv, const float* __restrict__ Wo,
                             bf16* __restrict__ Wt) {
  const int t = threadIdx.x;
  if (blockIdx.x < NROWS / 4) {
    // ---- LayerNorm: one wave per row, no barriers; lane holds 8 elems (2x float4) ----
    const int row = blockIdx.x * 4 + (t >> 6);
    const int l = t & 63;
    const float4* xr = reinterpret_cast<const float4*>(x + (size_t)row * DIM);
    const float4 v0 = xr[l * 2];
    const float4 v1 = xr[l * 2 + 1];
    float s = (v0.x + v0.y + v0.z + v0.w) + (v1.x + v1.y + v1.z + v1.w);
    float ss = v0.x * v0.x + v0.y * v0.y + v0.z * v0.z + v0.w * v0.w + v1.x * v1.x +
               v1.y * v1.y + v1.z * v1.z + v1.w * v1.w;
#pragma unroll
    for (int off = 1; off < 64; off <<= 1) {
      s += __shfl_xor(s, off);
      ss += __shfl_xor(ss, off);
    }
    const float mu = s * (1.0f / DIM);
    const float rs = rsqrtf(ss * (1.0f / DIM) - mu * mu + LN_EPS);
    const float4 g0 = reinterpret_cast<const float4*>(gamma)[l * 2];
    const float4 g1 = reinterpret_cast<const float4*>(gamma)[l * 2 + 1];
    const float4 b0 = reinterpret_cast<const float4*>(beta)[l * 2];
    const float4 b1 = reinterpret_cast<const float4*>(beta)[l * 2 + 1];
    bf16* o = xn + (size_t)row * DIM + l * 8;
    store_bf16x4(o, (v0.x - mu) * rs * g0.x + b0.x, (v0.y - mu) * rs * g0.y + b0.y,
                 (v0.z - mu) * rs * g0.z + b0.z, (v0.w - mu) * rs * g0.w + b0.w);
    store_bf16x4(o + 4, (v1.x - mu) * rs * g1.x + b1.x, (v1.y - mu) * rs * g1.y + b1.y,
                 (v1.z - mu) * rs * g1.z + b1.z, (v1.w - mu) * rs * g1.w + b1.w);
  } else {
    // ---- weight transpose + cast + scale: W[K][N] fp32 -> Wt[N][K] bf16 ----
    __shared__ float tile[32][33];
    const int idx = blockIdx.x - NROWS / 4;
    const int bx = idx & 15, by = (idx >> 4) & 15, z = idx >> 8;
    const float* __restrict__ W = (z == 0) ? Wq : (z == 1) ? Wk : (z == 2) ? Wv : Wo;
    const float scale = (z == 0) ? Q_SCALE_LOG2E : 1.0f;
    bf16* __restrict__ dst = Wt + (size_t)z * DIM * DIM;
    const int tx = t & 31, ty = t >> 5;  // 32 x 8
#pragma unroll
    for (int i = 0; i < 32; i += 8)
      tile[ty + i][tx] = W[(size_t)(by * 32 + ty + i) * DIM + bx * 32 + tx];
    __syncthreads();
#pragma unroll
    for (int i = 0; i < 32; i += 8)
      dst[(size_t)(bx * 32 + ty + i) * DIM + by * 32 + tx] =
          __float2bfloat16(tile[tx][ty + i] * scale);
  }
}

// ------ Fused QKV GEMM: C[M,1536] = A[M,512] @ Wt[1536,512]^T, 128x128 tile, dbuf ------
// q,k written [b][n][512]; V written TRANSPOSED [b][512][seq] via LDS-staged epilogue.
__launch_bounds__(256, 3)
__global__ void gemm_qkv_kernel(const bf16* __restrict__ A, const bf16* __restrict__ Bt,
                                bf16* __restrict__ qo, bf16* __restrict__ ko,
                                bf16* __restrict__ vto) {
  const int m0 = blockIdx.x * 128, n0g = blockIdx.y * 128;
  // union: K-loop uses sA/sB dbuf (32 KB); z==2 epilogue reuses as 128x136 transpose tile
  __shared__ __align__(16) char smem[128 * 136 * 2];  // 34816 B
  bf16* const sA = (bf16*)smem;             // [2][128*32]
  bf16* const sB = (bf16*)(smem + 16384);   // [2][128*32]
  bf16* const sT = (bf16*)smem;             // [128][136]
  const int t = threadIdx.x, w = t >> 6, l = t & 63;
  const int r = l & 15, g = l >> 4;
  const int wm = w >> 1, wn = w & 1;
  const int crow = w * 32 + (l >> 2);
  const int ccol = (l & 3) * 8;
  const bf16* gA = A + (size_t)(m0 + crow) * DIM + ccol;
  const bf16* gB = Bt + (size_t)(n0g + crow) * DIM + ccol;
  const int loff = w * 1024 + l * 8;
  f32x4 acc[4][4] = {};
  glds16(gA, sA + loff);
  glds16(gA + 16 * DIM, sA + loff + 512);
  glds16(gB, sB + loff);
  glds16(gB + 16 * DIM, sB + loff + 512);
  const int NK = DIM / 32;
  for (int ks = 0; ks < NK; ks++) {
    const int cur = ks & 1;
    __syncthreads();  // buf[cur] ready (drains vmcnt); all reads of buf[1-cur] done
    if (ks + 1 < NK) {
      const int k0n = (ks + 1) * 32;
      glds16(gA + k0n, sA + (1 - cur) * 4096 + loff);
      glds16(gA + 16 * DIM + k0n, sA + (1 - cur) * 4096 + loff + 512);
      glds16(gB + k0n, sB + (1 - cur) * 4096 + loff);
      glds16(gB + 16 * DIM + k0n, sB + (1 - cur) * 4096 + loff + 512);
    }
    short8 af[4], bfv[4];
#pragma unroll
    for (int i = 0; i < 4; i++)
      af[i] = *reinterpret_cast<const short8*>(
          &sA[cur * 4096 + (wm * 64 + i * 16 + r) * 32 + g * 8]);
#pragma unroll
    for (int j = 0; j < 4; j++)
      bfv[j] = *reinterpret_cast<const short8*>(
          &sB[cur * 4096 + (wn * 64 + j * 16 + r) * 32 + g * 8]);
#pragma unroll
    for (int i = 0; i < 4; i++)
#pragma unroll
      for (int j = 0; j < 4; j++) acc[i][j] = MFMA16(af[i], bfv[j], acc[i][j]);
  }
  const int z = n0g >> 9;  // which of q/k/v this n-tile belongs to
  const int b = m0 / SEQ;  // 128 | SEQ so whole block shares b
  if (z != 2) {
    bf16* __restrict__ outp = (z == 0) ? qo : ko;
    const int nc0 = (n0g & 511) + wn * 64;
#pragma unroll
    for (int i = 0; i < 4; i++)
#pragma unroll
      for (int j = 0; j < 4; j++)
#pragma unroll
        for (int reg = 0; reg < 4; reg++) {
          const int m = m0 + wm * 64 + i * 16 + g * 4 + reg;
          const int col = nc0 + j * 16 + r;
          outp[(size_t)m * DIM + col] = __float2bfloat16(acc[i][j][reg]);
        }
  } else {
    // transpose epilogue: acc -> sT[n][m] -> coalesced V^T writes (16B along seq)
    __syncthreads();  // done with sA/sB
#pragma unroll
    for (int i = 0; i < 4; i++)
#pragma unroll
      for (int j = 0; j < 4; j++)
        store_bf16x4(&sT[(wn * 64 + j * 16 + r) * 136 + wm * 64 + i * 16 + g * 4],
                     acc[i][j][0], acc[i][j][1], acc[i][j][2], acc[i][j][3]);
    __syncthreads();
    const int dr = t >> 1;        // 0..127: d-row within this 128-wide n-tile
    const int mc = (t & 1) * 64;  // m-half
    const int dcol = (n0g & 511) + dr;
    bf16* dst = vto + ((size_t)b * DIM + dcol) * SEQ + (m0 - b * SEQ) + mc;
#pragma unroll
    for (int uu = 0; uu < 8; uu++)
      *reinterpret_cast<uint4*>(dst + uu * 8) =
          *reinterpret_cast<const uint4*>(&sT[dr * 136 + mc + uu * 8]);
  }
}

// ---------------- Flash attention: S^T/O^T form, 4-wave blocks, j-split ----------------
// block = 256 thr (4 waves), 128 q-rows x one (b,h); wave owns 32 q-rows (2 strips of 16).
// Inner loop identical to the proven R9 kernel (sPt stride 72 frozen). K/V staging tile
// (16 KB) now shared by 4 waves -> per-wave glds halves; grid (bh, jh, it) puts the
// it-blocks sharing one (b,h) K/V panel on ids differing by 64 (≡0 mod 8) -> same XCD,
// so the 512 KB K+V panel stays L2-hot.
template <bool SPLIT>
__launch_bounds__(256, 4)
__global__ void attn_kernel(const bf16* __restrict__ q, const bf16* __restrict__ k,
                            const bf16* __restrict__ vt, bf16* __restrict__ opart,
                            float* __restrict__ lpart) {
  const int bh = blockIdx.x, jh = blockIdx.y, it = blockIdx.z;
  const int b = bh >> 3, h = bh & 7;
  const int t = threadIdx.x, wv = t >> 6, l = t & 63;
  const int r = l & 15, g = l >> 4;
  __shared__ __align__(16) bf16 sK[64 * 64];
  __shared__ __align__(16) bf16 sV[64 * 64];
  __shared__ __align__(16) bf16 sPt[4][2][16][72];  // [wave][strip][i][j+pad]; wave-private
  const int i0 = it * 128 + wv * 32;
  // Q B-frags: lane holds Q[i = i0+s*16+r][d = kc*32 + g*8 ..+7]
  const bf16* qp = q + ((size_t)(b * SEQ) + i0 + r) * DIM + h * DH;
  short8 qf[2][2];
#pragma unroll
  for (int s = 0; s < 2; s++)
#pragma unroll
    for (int kc = 0; kc < 2; kc++)
      qf[s][kc] = *reinterpret_cast<const short8*>(qp + s * 16 * DIM + kc * 32 + g * 8);
  f32x4 oacc[2][4] = {};       // O^T C-layout: row d = dt*16+g*4+reg, col i = r
  float lsum[2] = {0.f, 0.f};  // denominator partial for row i (fixed per lane)
  const int jbase = SPLIT ? jh * (SEQ / 2) : 0;
  // staging: wave wv stages chunks {2wv, 2wv+1}; lane n -> row n>>3, unit ((n&7)-(n>>3))&7
  const int srow8 = l >> 3;
  const int u = ((l & 7) - srow8) & 7;
  const bf16* kg = k + ((size_t)(b * SEQ) + jbase + wv * 16 + srow8) * DIM + h * DH + u * 8;
  const bf16* vg = vt + ((size_t)(b * DIM) + h * DH + wv * 16 + srow8) * SEQ + jbase + u * 8;
  const int loff = wv * 1024 + l * 8;
  // per-lane swizzled fragment-read offsets (constant across c/dt since c*16 % 8 == 0)
  const int e0 = 64 * r + 8 * ((g + r) & 7);      // k-chunk 0 (units g+0)
  const int e1 = 64 * r + 8 * ((4 + g + r) & 7);  // k-chunk 1 (units g+4)
  const int NJ = SPLIT ? (SEQ / 2) / 64 : SEQ / 64;
  for (int jt = 0; jt < NJ; jt++) {
    const int j0 = jt * 64;
#pragma unroll
    for (int cc = 0; cc < 2; cc++) {
      glds16(kg + (size_t)(j0 + cc * 8) * DIM, sK + loff + cc * 512);
      glds16(vg + (size_t)(cc * 8) * SEQ + j0, sV + loff + cc * 512);
    }
    __syncthreads();
    // S^T = K @ Q^T : A = K-frags (shared across strips), B = Q-frags
    f32x4 st[2][4];
#pragma unroll
    for (int c = 0; c < 4; c++) {
      const short8 kf0 = *reinterpret_cast<const short8*>(sK + 1024 * c + e0);
      const short8 kf1 = *reinterpret_cast<const short8*>(sK + 1024 * c + e1);
#pragma unroll
      for (int s = 0; s < 2; s++) {
        f32x4 a = {0.f, 0.f, 0.f, 0.f};
        a = MFMA16(kf0, qf[s][0], a);
        a = MFMA16(kf1, qf[s][1], a);
        st[s][c] = a;
      }
    }
    // p = exp2(S^T); scalar denominator; b64 P^T writes (4 consecutive j)
#pragma unroll
    for (int s = 0; s < 2; s++)
#pragma unroll
      for (int c = 0; c < 4; c++) {
        const float p0 = EXP2(st[s][c][0]);
        const float p1 = EXP2(st[s][c][1]);
        const float p2 = EXP2(st[s][c][2]);
        const float p3 = EXP2(st[s][c][3]);
        lsum[s] += (p0 + p1) + (p2 + p3);
        store_bf16x4(&sPt[wv][s][r][c * 16 + g * 4], p0, p1, p2, p3);
      }
    // O^T += V^T @ P^T
#pragma unroll
    for (int kc2 = 0; kc2 < 2; kc2++) {
      short8 pf[2];
#pragma unroll
      for (int s = 0; s < 2; s++)
        pf[s] = *reinterpret_cast<const short8*>(&sPt[wv][s][r][kc2 * 32 + g * 8]);
      const int ev = (kc2 == 0) ? e0 : e1;
#pragma unroll
      for (int dt = 0; dt < 4; dt++) {
        const short8 vf = *reinterpret_cast<const short8*>(sV + 1024 * dt + ev);
#pragma unroll
        for (int s = 0; s < 2; s++) oacc[s][dt] = MFMA16(vf, pf[s], oacc[s][dt]);
      }
    }
    __syncthreads();  // WAR guard before next glds overwrite
  }
  // fold denominator across the 4 lanes sharing row i=r (lanes l, l^16, l^32, l^48)
#pragma unroll
  for (int s = 0; s < 2; s++) {
    lsum[s] += __shfl_xor(lsum[s], 16);
    lsum[s] += __shfl_xor(lsum[s], 32);
  }
  // write unnormalized partials + row sums (proj kernel fuses the combine+normalize)
  const size_t obase = ((size_t)(SPLIT ? jh * 32 : 0) + bh) * SEQ;
#pragma unroll
  for (int s = 0; s < 2; s++) {
    const int i = i0 + s * 16 + r;
    if (l < 16) lpart[obase + i] = lsum[s];
#pragma unroll
    for (int dt = 0; dt < 4; dt++)
      store_bf16x4(opart + (obase + i) * 64 + dt * 16 + g * 4, oacc[s][dt][0], oacc[s][dt][1],
                   oacc[s][dt][2], oacc[s][dt][3]);
  }
  if (!SPLIT) {  // fallback: zero the second-half partials so the fused combine is a no-op add
    const size_t obase1 = ((size_t)32 + bh) * SEQ;
#pragma unroll
    for (int s = 0; s < 2; s++) {
      const int i = i0 + s * 16 + r;
      if (l < 16) lpart[obase1 + i] = 0.f;
#pragma unroll
      for (int dt = 0; dt < 4; dt++)
        store_bf16x4(opart + (obase1 + i) * 64 + dt * 16 + g * 4, 0.f, 0.f, 0.f, 0.f);
    }
  }
}

// ------ Output projection + FUSED attn-combine + bias + residual, 128x64 tile, fp32 out ------
// A[m][k] = (opart0 + opart1)[bh(m,k)][i(m)][d(k)] / (lpart0 + lpart1), staged to LDS in regs.
__launch_bounds__(256, 2)
__global__ void gemm_proj_kernel(const bf16* __restrict__ opart, const float* __restrict__ lpart,
                                 const bf16* __restrict__ Bt, const float* __restrict__ bo,
                                 const float* __restrict__ x, float* __restrict__ out) {
  const int m0 = blockIdx.x * 128, n0 = blockIdx.y * 64;
  __shared__ __align__(16) bf16 sA[128 * 32];
  __shared__ __align__(16) bf16 sB[64 * 32];
  const int t = threadIdx.x, w = t >> 6, l = t & 63;
  const int r = l & 15, g = l >> 4;
  const int wm = w >> 1, wn = w & 1;  // wave: rows wm*64.., cols wn*32..
  const int arow = t >> 2;
  const int acol = (t & 3) * 8;
  const bf16* gB = Bt + (size_t)(n0 + arow) * DIM + acol;
  f32x4 acc[4][2] = {};
  const int NK = DIM / 32;
  for (int ks = 0; ks < NK; ks++) {
    const int k0 = ks * 32;
    const int h = k0 >> 6;            // head for this whole k-step
    const int d0 = (k0 & 63) + acol;  // d within head
    // A combine-load into regs (2 chunks of 64 rows)
    uint4 areg[2];
#pragma unroll
    for (int c = 0; c < 2; c++) {
      const int m = m0 + c * 64 + arow;
      const int bb = m >> 11, ii = m & 2047;
      const size_t row0 = ((size_t)(bb * 8 + h)) * SEQ + ii;
      const size_t row1 = row0 + (size_t)32 * SEQ;
      const uint4 A0 = *reinterpret_cast<const uint4*>(opart + row0 * 64 + d0);
      const uint4 A1 = *reinterpret_cast<const uint4*>(opart + row1 * 64 + d0);
      const float inv = 1.0f / (lpart[row0] + lpart[row1]);
      const ushort* a0 = (const ushort*)&A0;
      const ushort* a1 = (const ushort*)&A1;
      bf16 rr[8];
#pragma unroll
      for (int e = 0; e < 8; e++)
        rr[e] = __float2bfloat16((B2F(a0[e]) + B2F(a1[e])) * inv);
      areg[c] = *reinterpret_cast<const uint4*>(rr);
    }
    const uint4 breg = *reinterpret_cast<const uint4*>(gB + k0);
    __syncthreads();  // all frag reads of previous tile done (WAR)
    *reinterpret_cast<uint4*>(&sA[(0 * 64 + arow) * 32 + acol]) = areg[0];
    *reinterpret_cast<uint4*>(&sA[(1 * 64 + arow) * 32 + acol]) = areg[1];
    *reinterpret_cast<uint4*>(&sB[arow * 32 + acol]) = breg;
    __syncthreads();  // writes visible
    short8 af[4], bfv[2];
#pragma unroll
    for (int i = 0; i < 4; i++)
      af[i] = *reinterpret_cast<const short8*>(&sA[(wm * 64 + i * 16 + r) * 32 + g * 8]);
#pragma unroll
    for (int j = 0; j < 2; j++)
      bfv[j] = *reinterpret_cast<const short8*>(&sB[(wn * 32 + j * 16 + r) * 32 + g * 8]);
#pragma unroll
    for (int i = 0; i < 4; i++)
#pragma unroll
      for (int j = 0; j < 2; j++) acc[i][j] = MFMA16(af[i], bfv[j], acc[i][j]);
  }
#pragma unroll
  for (int i = 0; i < 4; i++)
#pragma unroll
    for (int j = 0; j < 2; j++)
#pragma unroll
      for (int reg = 0; reg < 4; reg++) {
        const int m = m0 + wm * 64 + i * 16 + g * 4 + reg;
        const int col = n0 + wn * 32 + j * 16 + r;
        out[(size_t)m * DIM + col] = acc[i][j][reg] + bo[col] + x[(size_t)m * DIM + col];
      }
}

extern "C" void kernel_launch(void* const* d_in, const int* in_sizes, int n_in,
                              void* d_out, int out_size, void* d_ws, size_t ws_size,
                              hipStream_t stream) {
  (void)in_sizes; (void)n_in; (void)out_size;
  const float* x    = (const float*)d_in[0];
  const float* ln_g = (const float*)d_in[1];
  const float* ln_b = (const float*)d_in[2];
  const float* Wq   = (const float*)d_in[3];
  const float* Wk   = (const float*)d_in[4];
  const float* Wv   = (const float*)d_in[5];
  const float* Wo   = (const float*)d_in[6];
  const float* bo   = (const float*)d_in[7];
  float* out = (float*)d_out;
  char* ws = (char*)d_ws;
  // ws layout (MB): [0,8) xn | [8,10) wt x4 | [10,18) q | [18,26) k | [26,34) v^T
  //                 [34,50) opart (2 j-halves, bf16, unnormalized) | [50,50.5) lpart
  bf16* xn  = (bf16*)(ws);
  bf16* wt  = (bf16*)(ws + (8u << 20));
  bf16* qb  = (bf16*)(ws + (10u << 20));
  bf16* kb  = (bf16*)(ws + (18u << 20));
  bf16* vtb = (bf16*)(ws + (26u << 20));
  bf16* opart = (bf16*)(ws + (34u << 20));
  float* lpart = (float*)(ws + (50u << 20));
  const bool split = ws_size >= ((50u << 20) + (1u << 19));

  setup_kernel<<<NROWS / 4 + 1024, 256, 0, stream>>>(x, ln_g, ln_b, xn, Wq, Wk, Wv, Wo, wt);
  gemm_qkv_kernel<<<dim3(NROWS / 128, (3 * DIM) / 128), 256, 0, stream>>>(xn, wt, qb, kb, vtb);
  if (split) {
    attn_kernel<true><<<dim3(BATCH * NHEADS, 2, SEQ / 128), 256, 0, stream>>>(
        qb, kb, vtb, opart, lpart);
  } else {
    attn_kernel<false><<<dim3(BATCH * NHEADS, 1, SEQ / 128), 256, 0, stream>>>(
        qb, kb, vtb, opart, lpart);
  }
  gemm_proj_kernel<<<dim3(NROWS / 128, DIM / 64), 256, 0, stream>>>(
      opart, lpart, wt + 3 * DIM * DIM, bo, x, out);
}